// Round 1
// baseline (320.295 us; speedup 1.0000x reference)
//
#include <hip/hip_runtime.h>

#define SK_ITERS 50

// Fused: per-block thread-0 solves the 2x2 Sinkhorn-Knopp projection (50
// iters, precise IEEE fp32 division to match the XLA reference), broadcasts
// a = W00+W10, b = W01+W11 through LDS, then all threads do a float4
// grid-stride elementwise combine. Memory-bound: ~402 MB of HBM traffic.
__global__ __launch_bounds__(256) void sinkhorn_mix_kernel(
    const float* __restrict__ residual,
    const float* __restrict__ sublayer,
    const float* __restrict__ W_raw,
    float* __restrict__ out,
    long long n)            // total elements
{
    __shared__ float s_ab[2];

    if (threadIdx.x == 0) {
        // W_raw is row-major 2x2: [W00, W01, W10, W11]
        float w00 = fabsf(W_raw[0]) + 1e-8f;
        float w01 = fabsf(W_raw[1]) + 1e-8f;
        float w10 = fabsf(W_raw[2]) + 1e-8f;
        float w11 = fabsf(W_raw[3]) + 1e-8f;
        #pragma unroll 1
        for (int i = 0; i < SK_ITERS; ++i) {
            // row-normalize (axis=-1)
            float r0 = w00 + w01;
            float r1 = w10 + w11;
            w00 = w00 / r0; w01 = w01 / r0;
            w10 = w10 / r1; w11 = w11 / r1;
            // col-normalize (axis=-2)
            float c0 = w00 + w10;
            float c1 = w01 + w11;
            w00 = w00 / c0; w10 = w10 / c0;
            w01 = w01 / c1; w11 = w11 / c1;
        }
        s_ab[0] = w00 + w10;   // a
        s_ab[1] = w01 + w11;   // b
    }
    __syncthreads();

    const float a = s_ab[0];
    const float b = s_ab[1];

    const long long n4 = n >> 2;   // number of float4 chunks
    const float4* __restrict__ r4 = reinterpret_cast<const float4*>(residual);
    const float4* __restrict__ s4 = reinterpret_cast<const float4*>(sublayer);
    float4* __restrict__ o4 = reinterpret_cast<float4*>(out);

    const long long tid    = (long long)blockIdx.x * blockDim.x + threadIdx.x;
    const long long stride = (long long)gridDim.x * blockDim.x;

    for (long long i = tid; i < n4; i += stride) {
        float4 rv = r4[i];
        float4 sv = s4[i];
        float4 ov;
        ov.x = a * rv.x + b * sv.x;
        ov.y = a * rv.y + b * sv.y;
        ov.z = a * rv.z + b * sv.z;
        ov.w = a * rv.w + b * sv.w;
        o4[i] = ov;
    }

    // scalar tail (n not divisible by 4) — no-op for this problem size
    for (long long i = (n4 << 2) + tid; i < n; i += stride) {
        out[i] = a * residual[i] + b * sublayer[i];
    }
}

extern "C" void kernel_launch(void* const* d_in, const int* in_sizes, int n_in,
                              void* d_out, int out_size, void* d_ws, size_t ws_size,
                              hipStream_t stream) {
    const float* residual = (const float*)d_in[0];
    const float* sublayer = (const float*)d_in[1];
    const float* W_raw    = (const float*)d_in[2];
    float* out            = (float*)d_out;

    const long long n = (long long)out_size;   // 2*4096*4096 = 33,554,432

    const int block = 256;
    const int grid  = 2048;   // ~8 blocks/CU; grid-stride covers the rest

    sinkhorn_mix_kernel<<<grid, block, 0, stream>>>(residual, sublayer, W_raw, out, n);
}